// Round 4
// baseline (255.188 us; speedup 1.0000x reference)
//
#include <hip/hip_runtime.h>

// v5: ISA-forced memory-level parallelism, hardened form of v4.
// Nine single-output asm volatile loads (back-to-back issue, compiler cannot
// interleave waits), one s_waitcnt vmcnt(0) + sched_barrier(0) before use.
// 26 cache lines in flight per wave vs ~6 in v0 (28-VGPR serialization).
// LDS only for output transpose (9 KiB, v0's proven 0-conflict layout).
#define PTS 256

__global__ __launch_bounds__(256) void cov_proj_kernel(
    const float4* __restrict__ rot,     // (N,4) as float4
    const float*  __restrict__ mod,     // (1,)
    const float2* __restrict__ scale,   // (N,2) as float2
    const float*  __restrict__ p_k,     // (N,3)
    const float4* __restrict__ vm,      // (N,16) as 4x float4 per row
    float*        __restrict__ out,     // (N,9)
    int n)
{
    __shared__ __attribute__((aligned(16))) float lds_out[PTS * 9];  // 9 KiB

    const int t = threadIdx.x;
    const int base = blockIdx.x * PTS;
    const int i = base + t;
    const float m = mod[0];

    if (base + PTS <= n) {
        // ---- full block: batch-issue ALL loads at ISA level ----
        float4 a0, a1, a2, a3, q;
        float2 sc;
        float p0, p1, p2;
        const float4* vp = vm  + (size_t)4 * i;
        const float4* rp = rot + i;
        const float2* sp = scale + i;
        const float*  pp = p_k + (size_t)3 * i;

        // Back-to-back async issues; liveness keeps every dest distinct from
        // every later-used address reg, so async returns cannot corrupt.
        asm volatile("global_load_dwordx4 %0, %1, off"
                     : "=&v"(a0) : "v"(vp));
        asm volatile("global_load_dwordx4 %0, %1, off offset:16"
                     : "=&v"(a1) : "v"(vp));
        asm volatile("global_load_dwordx4 %0, %1, off offset:32"
                     : "=&v"(a2) : "v"(vp));
        asm volatile("global_load_dwordx4 %0, %1, off offset:48"
                     : "=&v"(a3) : "v"(vp));
        asm volatile("global_load_dwordx4 %0, %1, off"
                     : "=&v"(q) : "v"(rp));
        asm volatile("global_load_dwordx2 %0, %1, off"
                     : "=&v"(sc) : "v"(sp));
        asm volatile("global_load_dword %0, %1, off"
                     : "=&v"(p0) : "v"(pp));
        asm volatile("global_load_dword %0, %1, off offset:4"
                     : "=&v"(p1) : "v"(pp));
        asm volatile("global_load_dword %0, %1, off offset:8"
                     : "=&v"(p2) : "v"(pp));
        // Rule-18: explicit drain + scheduling fence so no consumer is
        // hoisted above the wait.
        asm volatile("s_waitcnt vmcnt(0)");
        __builtin_amdgcn_sched_barrier(0);

        float r = q.x, x = q.y, y = q.z, z = q.w;
        float s0 = m * sc.x;
        float s1 = m * sc.y;

        float R00 = 1.0f - 2.0f * (y * y + z * z);
        float R10 = 2.0f * (x * y + r * z);
        float R20 = 2.0f * (x * z - r * y);
        float R01 = 2.0f * (x * y - r * z);
        float R11 = 1.0f - 2.0f * (x * x + z * z);
        float R21 = 2.0f * (y * z + r * x);

        float u0 = s0 * R00, u1 = s0 * R10, u2 = s0 * R20;
        float v0 = s1 * R01, v1 = s1 * R11, v2 = s1 * R21;

        float* o = &lds_out[9 * t];   // banks (9t+j)%32: <=2 lanes/bank (free)
        o[0] = a0.x * u0 + a1.x * u1 + a2.x * u2;
        o[1] = a0.x * v0 + a1.x * v1 + a2.x * v2;
        o[2] = a0.x * p0 + a1.x * p1 + a2.x * p2 + a3.x;
        o[3] = a0.y * u0 + a1.y * u1 + a2.y * u2;
        o[4] = a0.y * v0 + a1.y * v1 + a2.y * v2;
        o[5] = a0.y * p0 + a1.y * p1 + a2.y * p2 + a3.y;
        o[6] = a0.z * u0 + a1.z * u1 + a2.z * u2;
        o[7] = a0.z * v0 + a1.z * v1 + a2.z * v2;
        o[8] = a0.z * p0 + a1.z * p1 + a2.z * p2 + a3.z;
    } else if (i < n) {
        // ---- tail block (1 of 7813): plain guarded path ----
        float4 q = rot[i];
        float r = q.x, x = q.y, y = q.z, z = q.w;
        float2 sc = scale[i];
        float s0 = m * sc.x;
        float s1 = m * sc.y;

        float R00 = 1.0f - 2.0f * (y * y + z * z);
        float R10 = 2.0f * (x * y + r * z);
        float R20 = 2.0f * (x * z - r * y);
        float R01 = 2.0f * (x * y - r * z);
        float R11 = 1.0f - 2.0f * (x * x + z * z);
        float R21 = 2.0f * (y * z + r * x);

        float u0 = s0 * R00, u1 = s0 * R10, u2 = s0 * R20;
        float v0 = s1 * R01, v1 = s1 * R11, v2 = s1 * R21;

        float p0 = p_k[3 * i + 0];
        float p1 = p_k[3 * i + 1];
        float p2 = p_k[3 * i + 2];
        float4 a0 = vm[4 * i + 0];
        float4 a1 = vm[4 * i + 1];
        float4 a2 = vm[4 * i + 2];
        float4 a3 = vm[4 * i + 3];

        float* o = &lds_out[9 * t];
        o[0] = a0.x * u0 + a1.x * u1 + a2.x * u2;
        o[1] = a0.x * v0 + a1.x * v1 + a2.x * v2;
        o[2] = a0.x * p0 + a1.x * p1 + a2.x * p2 + a3.x;
        o[3] = a0.y * u0 + a1.y * u1 + a2.y * u2;
        o[4] = a0.y * v0 + a1.y * v1 + a2.y * v2;
        o[5] = a0.y * p0 + a1.y * p1 + a2.y * p2 + a3.y;
        o[6] = a0.z * u0 + a1.z * u1 + a2.z * u2;
        o[7] = a0.z * v0 + a1.z * v1 + a2.z * v2;
        o[8] = a0.z * p0 + a1.z * p1 + a2.z * p2 + a3.z;
    }
    __syncthreads();

    const int points = min(PTS, n - base);
    const size_t out_base = (size_t)base * 9;

    if (points == PTS) {
        // 2304 floats = 576 float4, contiguous & 16B-aligned
        // (out_base*4 = blockIdx*9216 bytes, 9216 % 16 == 0).
        const float4* lo4 = (const float4*)lds_out;
        float4* go4 = (float4*)(out + out_base);
        #pragma unroll
        for (int k = t; k < (PTS * 9) / 4; k += 256) go4[k] = lo4[k];
    } else {
        const int total = points * 9;
        for (int k = t; k < total; k += 256) out[out_base + k] = lds_out[k];
    }
}

extern "C" void kernel_launch(void* const* d_in, const int* in_sizes, int n_in,
                              void* d_out, int out_size, void* d_ws, size_t ws_size,
                              hipStream_t stream) {
    const float4* rot   = (const float4*)d_in[0];
    const float*  mod   = (const float*)d_in[1];
    const float2* scale = (const float2*)d_in[2];
    const float*  p_k   = (const float*)d_in[3];
    const float4* vm    = (const float4*)d_in[4];
    float* out = (float*)d_out;

    int n = in_sizes[0] / 4;  // rot has N*4 elements
    int block = 256;
    int grid = (n + PTS - 1) / PTS;
    cov_proj_kernel<<<grid, block, 0, stream>>>(rot, mod, scale, p_k, vm, out, n);
}